// Round 9
// baseline (16783.386 us; speedup 1.0000x reference)
//
#include <hip/hip_runtime.h>
#include <hip/hip_fp16.h>
#include <math.h>

// EchoStateNetwork: B=32, S=4096, I=64, R=1024, O=8, fp32.
// Round-8 structure (fp16 W_res in 32 VGPRs, proven absmax 0.0156) with two
// transport deltas:
//  (1) epoch-array barrier: per-WG relaxed store ep[m]=t+1 + 32-lane ballot
//      poll (no 32-deep atomic-RMW serialization on one line);
//  (2) T14 async x-prefetch: x[t+1] global_load issued BEFORE the mid-step
//      barrier; raw s_barrier + manual s_waitcnt vmcnt(1) drains only the
//      rbuf store, so the x HBM latency rides across the barrier and the
//      ds_write lands in the shadow.

#define NS 4096
#define NI 64
#define NR 1024
#define NO 8
#define NB 32
#define NGRP 8
#define GPP 32      // WGs per group
#define CPG 4       // chains per group
#define WROWS 32    // W_res rows per WG
#define NT 512
#define WOC (NI + NR + 1)   // padded W_out row stride in LDS

#define ATLF(p)   __hip_atomic_load((p), __ATOMIC_RELAXED, __HIP_MEMORY_SCOPE_AGENT)
#define ATSF(p,v) __hip_atomic_store((p), (v), __ATOMIC_RELAXED, __HIP_MEMORY_SCOPE_AGENT)
#define ATLU(p)   __hip_atomic_load((p), __ATOMIC_RELAXED, __HIP_MEMORY_SCOPE_AGENT)
#define ATSU(p,v) __hip_atomic_store((p), (v), __ATOMIC_RELAXED, __HIP_MEMORY_SCOPE_AGENT)

__global__ void init_cnt_kernel(unsigned int* cnt) {
  cnt[threadIdx.x] = 0u;   // zero 4 KB of epoch slots
}

__global__ __launch_bounds__(NT)
__attribute__((amdgpu_waves_per_eu(2, 2)))
void esn_scan(const float* __restrict__ x, const float* __restrict__ Win,
              const float* __restrict__ Wres, const float* __restrict__ Wout,
              float* __restrict__ out, unsigned int* __restrict__ cnt,
              float* __restrict__ rbuf)
{
  extern __shared__ float dynpad[];  // 64 KB occupancy shaping (dispatch-reserved)
  const int wg  = blockIdx.x;
  const int g   = wg & 7;    // group
  const int m   = wg >> 3;   // member 0..31
  const int tid = threadIdx.x;
  const int w   = tid >> 6;  // wave 0..7
  const int l   = tid & 63;  // lane

  __shared__ float r_lds[CPG][NR];         // 16 KB: full r_{t-1}, 4 chains
  __shared__ float x_lds[3][CPG][NI + 1];  // mod-3 ring: x[t-1], x[t], x[t+1]
  __shared__ float win_s[WROWS][NI + 1];   // 8.3 KB
  __shared__ float wout_s[NO][WOC];        // 34.8 KB: FULL W_out

  // never-true guard keeps dynpad referenced
  if (x[0] == 1234.5678f) { dynpad[tid] = 1.f; out[tid] = dynpad[tid ^ 1]; }

  // ---- startup: weights -> fp16 register pairs / LDS ----
  __half2 wh[32];  // wh[(r*4+s)*2+p] = W_res[32m+4w+r][4l+256s+2p .. +1]
  {
    const int grow0 = 32 * m + 4 * w;
    #pragma unroll
    for (int r = 0; r < 4; ++r)
      #pragma unroll
      for (int s = 0; s < 4; ++s) {
        float4 t4 = *(const float4*)&Wres[(size_t)(grow0 + r) * NR + 4 * l + 256 * s];
        wh[(r * 4 + s) * 2 + 0] = __halves2half2(__float2half(t4.x), __float2half(t4.y));
        wh[(r * 4 + s) * 2 + 1] = __halves2half2(__float2half(t4.z), __float2half(t4.w));
      }
  }
  for (int idx = tid; idx < WROWS * NI; idx += NT) {
    int rr = idx >> 6, ii = idx & 63;
    win_s[rr][ii] = Win[(32 * m + rr) * NI + ii];
  }
  for (int idx = tid; idx < NO * (NI + NR); idx += NT) {
    int o = idx / (NI + NR), f = idx % (NI + NR);
    wout_s[o][f] = Wout[o * (NI + NR) + f];
  }
  if (tid < 256) {  // x[0] into ring slot 0
    const int c = tid >> 6, ii = tid & 63;
    x_lds[0][c][ii] = x[(size_t)(4 * g + c) * NS * NI + ii];
  }
  __syncthreads();

  unsigned int* ep = cnt + g * 64;  // 32 epoch dwords in one 128B line (256B apart per group)

  // x-prefetch mapping: 32 lanes/wave, idx = 32w + l covers 0..255
  const int pidx = 32 * w + (l & 31);
  const int pc = pidx >> 6, pii = pidx & 63;
  const float* xq = x + (size_t)(4 * g + pc) * NS * NI + NI + pii;  // -> x[1]

  for (int t = 0; t < NS; ++t) {
    const int par = t & 1, pprev = par ^ 1;

    // ---- Phase L: gather r_{t-1} (relaxed agent loads -> LDS) ----
    if (t > 0) {
      const float* rp = rbuf + (size_t)pprev * NB * NR + (size_t)(4 * g) * NR;
      float tv[8];
      #pragma unroll
      for (int j = 0; j < 8; ++j) tv[j] = ATLF(rp + tid + 512 * j);
      #pragma unroll
      for (int j = 0; j < 8; ++j) ((float*)r_lds)[tid + 512 * j] = tv[j];
    } else {
      for (int idx = tid; idx < CPG * NR; idx += NT) ((float*)r_lds)[idx] = 0.f;
    }
    __syncthreads();

    // ---- dot: acc[r][c]; fp16 weights cvt once, used 4x ----
    float acc[4][4];
    #pragma unroll
    for (int r = 0; r < 4; ++r)
      #pragma unroll
      for (int c = 0; c < 4; ++c) acc[r][c] = 0.f;
    #pragma unroll
    for (int s = 0; s < 4; ++s) {
      float4 f0 = *(const float4*)&r_lds[0][4 * l + 256 * s];
      float4 f1 = *(const float4*)&r_lds[1][4 * l + 256 * s];
      float4 f2 = *(const float4*)&r_lds[2][4 * l + 256 * s];
      float4 f3 = *(const float4*)&r_lds[3][4 * l + 256 * s];
      #pragma unroll
      for (int r = 0; r < 4; ++r) {
        const __half2 ha = wh[(r * 4 + s) * 2 + 0];
        const __half2 hb = wh[(r * 4 + s) * 2 + 1];
        const float w0 = __half2float(__low2half(ha));
        const float w1 = __half2float(__high2half(ha));
        const float w2 = __half2float(__low2half(hb));
        const float w3 = __half2float(__high2half(hb));
        acc[r][0] = fmaf(w0, f0.x, acc[r][0]);
        acc[r][0] = fmaf(w1, f0.y, acc[r][0]);
        acc[r][0] = fmaf(w2, f0.z, acc[r][0]);
        acc[r][0] = fmaf(w3, f0.w, acc[r][0]);
        acc[r][1] = fmaf(w0, f1.x, acc[r][1]);
        acc[r][1] = fmaf(w1, f1.y, acc[r][1]);
        acc[r][1] = fmaf(w2, f1.z, acc[r][1]);
        acc[r][1] = fmaf(w3, f1.w, acc[r][1]);
        acc[r][2] = fmaf(w0, f2.x, acc[r][2]);
        acc[r][2] = fmaf(w1, f2.y, acc[r][2]);
        acc[r][2] = fmaf(w2, f2.z, acc[r][2]);
        acc[r][2] = fmaf(w3, f2.w, acc[r][2]);
        acc[r][3] = fmaf(w0, f3.x, acc[r][3]);
        acc[r][3] = fmaf(w1, f3.y, acc[r][3]);
        acc[r][3] = fmaf(w2, f3.z, acc[r][3]);
        acc[r][3] = fmaf(w3, f3.w, acc[r][3]);
      }
    }

    // ---- paired butterfly: 16 sums across 64 lanes ----
    float v[16];
    #pragma unroll
    for (int k = 0; k < 16; ++k) v[k] = acc[k >> 2][k & 3];
    #pragma unroll
    for (int lev = 0; lev < 4; ++lev) {
      const int d = 1 << lev;
      const int n = 16 >> lev;
      #pragma unroll
      for (int i = 0; i < n / 2; ++i) {
        float a  = v[2 * i]     + __shfl_xor(v[2 * i],     d);
        float bb = v[2 * i + 1] + __shfl_xor(v[2 * i + 1], d);
        v[i] = (l & d) ? bb : a;
      }
    }
    float dsum = v[0];
    dsum += __shfl_xor(dsum, 16);
    dsum += __shfl_xor(dsum, 32);

    // ---- finalize: pin + tanh + relaxed agent store ----
    if (l < 16) {
      const int r = l >> 2, c = l & 3;
      const int lrow = 4 * w + r;
      const int grow = 32 * m + lrow;
      float pin = 0.f;
      #pragma unroll
      for (int ii = 0; ii < NI; ++ii)
        pin = fmaf(win_s[lrow][ii], x_lds[t % 3][c][ii], pin);
      float rv = tanhf(dsum + pin);
      ATSF(rbuf + (size_t)par * NB * NR + (size_t)(4 * g + c) * NR + grow, rv);
    }

    // ---- T14 split: issue x[t+1] load NOW (rides across the barrier) ----
    float xreg;
    if (t + 1 < NS) {
      asm volatile("" ::: "memory");   // keep the rbuf store above
      if (l < 32)
        asm volatile("global_load_dword %0, %1, off"
                     : "=v"(xreg) : "v"(xq) : "memory");
      // per-wave vmem queue = [rbuf store, x load]; drain the store only
      asm volatile("s_waitcnt vmcnt(1)" ::: "memory");
    } else {
      asm volatile("s_waitcnt vmcnt(0)" ::: "memory");
    }
    __builtin_amdgcn_s_barrier();      // all waves: rbuf stores at L3
    asm volatile("" ::: "memory");

    // ---- arrive: plain epoch store (no RMW) ----
    if (tid == 0) ATSU(ep + m, (unsigned)(t + 1));

    // ---- shadow work ----
    if (t + 1 < NS) {
      asm volatile("s_waitcnt vmcnt(0)" ::: "memory");  // x load landed
      if (l < 32) x_lds[(t + 1) % 3][pc][pii] = xreg;
      xq += NI;
    }
    if (t > 0 && m == ((t - 1) & 31)) {   // rotating local output reduction
      const int grp = tid >> 4;
      const int j   = tid & 15;
      const int c   = grp >> 3, o = grp & 7;
      float s = 0.f;
      #pragma unroll
      for (int k = 0; k < 16; ++k) {
        const int fb = 64 * k + 4 * j;
        float4 rr = *(const float4*)&r_lds[c][fb];
        float4 ww = *(const float4*)&wout_s[o][NI + fb];
        s = fmaf(ww.x, rr.x, s); s = fmaf(ww.y, rr.y, s);
        s = fmaf(ww.z, rr.z, s); s = fmaf(ww.w, rr.w, s);
      }
      #pragma unroll
      for (int e = 0; e < 4; ++e)
        s = fmaf(wout_s[o][4 * j + e], x_lds[(t + 2) % 3][c][4 * j + e], s);
      s += __shfl_xor(s, 1); s += __shfl_xor(s, 2);
      s += __shfl_xor(s, 4); s += __shfl_xor(s, 8);
      if (j == 0) out[((size_t)(4 * g + c) * NS + (t - 1)) * NO + o] = s;
    }

    // ---- wait: 32-lane ballot poll of the epoch line ----
    if (tid < 32) {
      const unsigned target = (unsigned)(t + 1);
      while (!__all((int)(ATLU(ep + tid) >= target))) { }
    }
    __syncthreads();
  }

  // ---- final output row t = NS-1 (one WG per group; r_{NS-1} from rbuf) ----
  if (m == 31) {
    const int fpar = (NS - 1) & 1;
    const float* rp = rbuf + (size_t)fpar * NB * NR + (size_t)(4 * g) * NR;
    float tv[8];
    #pragma unroll
    for (int j = 0; j < 8; ++j) tv[j] = ATLF(rp + tid + 512 * j);
    #pragma unroll
    for (int j = 0; j < 8; ++j) ((float*)r_lds)[tid + 512 * j] = tv[j];
    __syncthreads();
    const int grp = tid >> 4;
    const int j   = tid & 15;
    const int c   = grp >> 3, o = grp & 7;
    float s = 0.f;
    #pragma unroll
    for (int k = 0; k < 16; ++k) {
      const int fb = 64 * k + 4 * j;
      float4 rr = *(const float4*)&r_lds[c][fb];
      float4 ww = *(const float4*)&wout_s[o][NI + fb];
      s = fmaf(ww.x, rr.x, s); s = fmaf(ww.y, rr.y, s);
      s = fmaf(ww.z, rr.z, s); s = fmaf(ww.w, rr.w, s);
    }
    #pragma unroll
    for (int e = 0; e < 4; ++e)
      s = fmaf(wout_s[o][4 * j + e], x_lds[(NS - 1) % 3][c][4 * j + e], s);
    s += __shfl_xor(s, 1); s += __shfl_xor(s, 2);
    s += __shfl_xor(s, 4); s += __shfl_xor(s, 8);
    if (j == 0) out[((size_t)(4 * g + c) * NS + (NS - 1)) * NO + o] = s;
  }
}

extern "C" void kernel_launch(void* const* d_in, const int* in_sizes, int n_in,
                              void* d_out, int out_size, void* d_ws, size_t ws_size,
                              hipStream_t stream) {
  const float* x    = (const float*)d_in[0];
  const float* Win  = (const float*)d_in[1];
  const float* Wres = (const float*)d_in[2];
  const float* Wout = (const float*)d_in[3];
  float* out = (float*)d_out;

  char* ws = (char*)d_ws;
  unsigned int* cnt = (unsigned int*)ws;      // 4 KB epoch slots (8 groups x 256 B)
  float* rbuf = (float*)(ws + 4096);          // 2*32*1024*4 = 256 KB

  hipLaunchKernelGGL(init_cnt_kernel, dim3(1), dim3(1024), 0, stream, cnt);
  hipLaunchKernelGGL(esn_scan, dim3(256), dim3(NT), 64 * 1024, stream,
                     x, Win, Wres, Wout, out, cnt, rbuf);
}

// Round 15
// 11898.590 us; speedup vs baseline: 1.4105x; 1.4105x over previous
//
#include <hip/hip_runtime.h>
#include <hip/hip_fp16.h>
#include <math.h>

// EchoStateNetwork: B=32, S=4096, I=64, R=1024, O=8, fp32.
// EXACT round-8 structure (proven 14.92 ms, absmax 0.0156) with ONE delta:
// the pin dot (W_in[row].x[t], previously a 64-iter serial FMA chain run
// by 16 lanes on the critical path) is now computed by all 64 lanes:
// pair p=l&15 (row 4w+(p>>2), chain p&3), chunk q=l>>4 (16 floats), then
// shfl_xor(16)+shfl_xor(32) -> lane l<16 holds the same pin as r8.
// win_s/x_lds strides padded to 68 floats so float4 bases are 16B-aligned.
// Everything else byte-identical to r8: fp16 W_res in 32 VGPRs, RELAXED
// agent-scope atomics for rbuf + counter barrier, arrive-early/wait-late,
// shadow rotating local output reduction, mod-3 x ring, 64KB dynamic LDS.

#define NS 4096
#define NI 64
#define NR 1024
#define NO 8
#define NB 32
#define NGRP 8
#define GPP 32      // WGs per group
#define CPG 4       // chains per group
#define WROWS 32    // W_res rows per WG
#define NT 512
#define XPAD 68             // padded row stride (272B, 16B-aligned)
#define WOC (NI + NR + 1)   // W_out row stride in LDS (as r8)

#define ATLF(p)   __hip_atomic_load((p), __ATOMIC_RELAXED, __HIP_MEMORY_SCOPE_AGENT)
#define ATSF(p,v) __hip_atomic_store((p), (v), __ATOMIC_RELAXED, __HIP_MEMORY_SCOPE_AGENT)
#define ATLU(p)   __hip_atomic_load((p), __ATOMIC_RELAXED, __HIP_MEMORY_SCOPE_AGENT)
#define ATAU(p,v) __hip_atomic_fetch_add((p), (v), __ATOMIC_RELAXED, __HIP_MEMORY_SCOPE_AGENT)

__global__ void init_cnt_kernel(unsigned int* cnt) {
  cnt[threadIdx.x] = 0u;   // zero 4 KB of barrier counters
}

__global__ __launch_bounds__(NT)
__attribute__((amdgpu_waves_per_eu(2, 2)))
void esn_scan(const float* __restrict__ x, const float* __restrict__ Win,
              const float* __restrict__ Wres, const float* __restrict__ Wout,
              float* __restrict__ out, unsigned int* __restrict__ cnt,
              float* __restrict__ rbuf)
{
  extern __shared__ float dynpad[];  // 64 KB occupancy shaping (dispatch-reserved)
  const int wg  = blockIdx.x;
  const int g   = wg & 7;    // group
  const int m   = wg >> 3;   // member 0..31
  const int tid = threadIdx.x;
  const int w   = tid >> 6;  // wave 0..7
  const int l   = tid & 63;  // lane

  __shared__ float r_lds[CPG][NR];        // 16 KB: full r_{t-1}, 4 chains
  __shared__ float x_lds[3][CPG][XPAD];   // mod-3 ring (272B rows, aligned)
  __shared__ float win_s[WROWS][XPAD];    // 8.7 KB (272B rows, aligned)
  __shared__ float wout_s[NO][WOC];       // 34.8 KB: FULL W_out

  // never-true guard keeps dynpad referenced
  if (x[0] == 1234.5678f) { dynpad[tid] = 1.f; out[tid] = dynpad[tid ^ 1]; }

  // ---- startup: weights -> fp16 register pairs / LDS ----
  __half2 wh[32];  // wh[(r*4+s)*2+p] = W_res[32m+4w+r][4l+256s+2p .. +1]
  {
    const int grow0 = 32 * m + 4 * w;
    #pragma unroll
    for (int r = 0; r < 4; ++r)
      #pragma unroll
      for (int s = 0; s < 4; ++s) {
        float4 t4 = *(const float4*)&Wres[(size_t)(grow0 + r) * NR + 4 * l + 256 * s];
        wh[(r * 4 + s) * 2 + 0] = __halves2half2(__float2half(t4.x), __float2half(t4.y));
        wh[(r * 4 + s) * 2 + 1] = __halves2half2(__float2half(t4.z), __float2half(t4.w));
      }
  }
  for (int idx = tid; idx < WROWS * NI; idx += NT) {
    int rr = idx >> 6, ii = idx & 63;
    win_s[rr][ii] = Win[(32 * m + rr) * NI + ii];
  }
  for (int idx = tid; idx < NO * (NI + NR); idx += NT) {
    int o = idx / (NI + NR), f = idx % (NI + NR);
    wout_s[o][f] = Wout[o * (NI + NR) + f];
  }
  if (tid < 256) {  // x[0] into ring slot 0
    const int c = tid >> 6, ii = tid & 63;
    x_lds[0][c][ii] = x[(size_t)(4 * g + c) * NS * NI + ii];
  }
  __syncthreads();

  unsigned int* bcp = cnt + g * 64;  // barrier counter (256 B apart per group)

  for (int t = 0; t < NS; ++t) {
    const int par = t & 1, pprev = par ^ 1;

    // ---- Phase L: gather r_{t-1} (relaxed agent loads -> LDS) ----
    if (t > 0) {
      const float* rp = rbuf + (size_t)pprev * NB * NR + (size_t)(4 * g) * NR;
      float tv[8];
      #pragma unroll
      for (int j = 0; j < 8; ++j) tv[j] = ATLF(rp + tid + 512 * j);
      #pragma unroll
      for (int j = 0; j < 8; ++j) ((float*)r_lds)[tid + 512 * j] = tv[j];
    } else {
      for (int idx = tid; idx < CPG * NR; idx += NT) ((float*)r_lds)[idx] = 0.f;
    }
    __syncthreads();

    // ---- dot: acc[r][c]; fp16 weights cvt once, used 4x ----
    float acc[4][4];
    #pragma unroll
    for (int r = 0; r < 4; ++r)
      #pragma unroll
      for (int c = 0; c < 4; ++c) acc[r][c] = 0.f;
    #pragma unroll
    for (int s = 0; s < 4; ++s) {
      float4 f0 = *(const float4*)&r_lds[0][4 * l + 256 * s];
      float4 f1 = *(const float4*)&r_lds[1][4 * l + 256 * s];
      float4 f2 = *(const float4*)&r_lds[2][4 * l + 256 * s];
      float4 f3 = *(const float4*)&r_lds[3][4 * l + 256 * s];
      #pragma unroll
      for (int r = 0; r < 4; ++r) {
        const __half2 ha = wh[(r * 4 + s) * 2 + 0];
        const __half2 hb = wh[(r * 4 + s) * 2 + 1];
        const float w0 = __half2float(__low2half(ha));
        const float w1 = __half2float(__high2half(ha));
        const float w2 = __half2float(__low2half(hb));
        const float w3 = __half2float(__high2half(hb));
        acc[r][0] = fmaf(w0, f0.x, acc[r][0]);
        acc[r][0] = fmaf(w1, f0.y, acc[r][0]);
        acc[r][0] = fmaf(w2, f0.z, acc[r][0]);
        acc[r][0] = fmaf(w3, f0.w, acc[r][0]);
        acc[r][1] = fmaf(w0, f1.x, acc[r][1]);
        acc[r][1] = fmaf(w1, f1.y, acc[r][1]);
        acc[r][1] = fmaf(w2, f1.z, acc[r][1]);
        acc[r][1] = fmaf(w3, f1.w, acc[r][1]);
        acc[r][2] = fmaf(w0, f2.x, acc[r][2]);
        acc[r][2] = fmaf(w1, f2.y, acc[r][2]);
        acc[r][2] = fmaf(w2, f2.z, acc[r][2]);
        acc[r][2] = fmaf(w3, f2.w, acc[r][2]);
        acc[r][3] = fmaf(w0, f3.x, acc[r][3]);
        acc[r][3] = fmaf(w1, f3.y, acc[r][3]);
        acc[r][3] = fmaf(w2, f3.z, acc[r][3]);
        acc[r][3] = fmaf(w3, f3.w, acc[r][3]);
      }
    }

    // ---- paired butterfly: 16 sums across 64 lanes ----
    float v[16];
    #pragma unroll
    for (int k = 0; k < 16; ++k) v[k] = acc[k >> 2][k & 3];
    #pragma unroll
    for (int lev = 0; lev < 4; ++lev) {
      const int d = 1 << lev;
      const int n = 16 >> lev;
      #pragma unroll
      for (int i = 0; i < n / 2; ++i) {
        float a  = v[2 * i]     + __shfl_xor(v[2 * i],     d);
        float bb = v[2 * i + 1] + __shfl_xor(v[2 * i + 1], d);
        v[i] = (l & d) ? bb : a;
      }
    }
    float dsum = v[0];
    dsum += __shfl_xor(dsum, 16);
    dsum += __shfl_xor(dsum, 32);

    // ---- parallel pin: pair p=l&15 (row 4w+(p>>2), chain p&3), chunk l>>4 ----
    float pin;
    {
      const int p = l & 15;
      const int prow = 4 * w + (p >> 2);
      const int pc = p & 3;
      const int cb = (l >> 4) * 16;   // 16-float chunk, 64B offset: aligned
      const float* wr = &win_s[prow][cb];
      const float* xr = &x_lds[t % 3][pc][cb];
      float4 a0 = *(const float4*)&wr[0];
      float4 a1 = *(const float4*)&wr[4];
      float4 a2 = *(const float4*)&wr[8];
      float4 a3 = *(const float4*)&wr[12];
      float4 b0 = *(const float4*)&xr[0];
      float4 b1 = *(const float4*)&xr[4];
      float4 b2 = *(const float4*)&xr[8];
      float4 b3 = *(const float4*)&xr[12];
      pin = a0.x * b0.x;
      pin = fmaf(a0.y, b0.y, pin); pin = fmaf(a0.z, b0.z, pin);
      pin = fmaf(a0.w, b0.w, pin);
      pin = fmaf(a1.x, b1.x, pin); pin = fmaf(a1.y, b1.y, pin);
      pin = fmaf(a1.z, b1.z, pin); pin = fmaf(a1.w, b1.w, pin);
      pin = fmaf(a2.x, b2.x, pin); pin = fmaf(a2.y, b2.y, pin);
      pin = fmaf(a2.z, b2.z, pin); pin = fmaf(a2.w, b2.w, pin);
      pin = fmaf(a3.x, b3.x, pin); pin = fmaf(a3.y, b3.y, pin);
      pin = fmaf(a3.z, b3.z, pin); pin = fmaf(a3.w, b3.w, pin);
      pin += __shfl_xor(pin, 16);
      pin += __shfl_xor(pin, 32);   // lane l: full pin for pair p=l&15
    }

    // ---- finalize: tanh + relaxed agent store ----
    if (l < 16) {
      const int r = l >> 2, c = l & 3;
      const int grow = 32 * m + 4 * w + r;
      float rv = tanhf(dsum + pin);
      ATSF(rbuf + (size_t)par * NB * NR + (size_t)(4 * g + c) * NR + grow, rv);
    }

    // ---- arrive (early): all this WG's stores drained by the barrier ----
    __syncthreads();  // emits s_waitcnt vmcnt(0) per wave before s_barrier
    if (tid == 0)
      ATAU(bcp, 1u);

    // ---- shadow work while the group converges ----
    if (t + 1 < NS && tid < 256) {
      const int c = tid >> 6, ii = tid & 63;
      x_lds[(t + 1) % 3][c][ii] = x[((size_t)(4 * g + c) * NS + (t + 1)) * NI + ii];
    }
    if (t > 0 && m == ((t - 1) & 31)) {
      const int grp = tid >> 4;   // 0..31 -> (c,o)
      const int j   = tid & 15;
      const int c   = grp >> 3, o = grp & 7;
      float s = 0.f;
      #pragma unroll
      for (int k = 0; k < 16; ++k) {
        const int fb = 64 * k + 4 * j;
        float4 rr = *(const float4*)&r_lds[c][fb];
        float4 ww = *(const float4*)&wout_s[o][NI + fb];
        s = fmaf(ww.x, rr.x, s); s = fmaf(ww.y, rr.y, s);
        s = fmaf(ww.z, rr.z, s); s = fmaf(ww.w, rr.w, s);
      }
      #pragma unroll
      for (int e = 0; e < 4; ++e)
        s = fmaf(wout_s[o][4 * j + e], x_lds[(t + 2) % 3][c][4 * j + e], s);
      s += __shfl_xor(s, 1); s += __shfl_xor(s, 2);
      s += __shfl_xor(s, 4); s += __shfl_xor(s, 8);
      if (j == 0) out[((size_t)(4 * g + c) * NS + (t - 1)) * NO + o] = s;
    }

    // ---- wait (late) ----
    if (tid == 0) {
      const unsigned target = (unsigned)(GPP * (t + 1));
      while (ATLU(bcp) < target) { }
    }
    __syncthreads();
  }

  // ---- final output row t = NS-1 (one WG per group; r_{NS-1} from rbuf) ----
  if (m == 31) {
    const int fpar = (NS - 1) & 1;
    const float* rp = rbuf + (size_t)fpar * NB * NR + (size_t)(4 * g) * NR;
    float tv[8];
    #pragma unroll
    for (int j = 0; j < 8; ++j) tv[j] = ATLF(rp + tid + 512 * j);
    #pragma unroll
    for (int j = 0; j < 8; ++j) ((float*)r_lds)[tid + 512 * j] = tv[j];
    __syncthreads();
    const int grp = tid >> 4;
    const int j   = tid & 15;
    const int c   = grp >> 3, o = grp & 7;
    float s = 0.f;
    #pragma unroll
    for (int k = 0; k < 16; ++k) {
      const int fb = 64 * k + 4 * j;
      float4 rr = *(const float4*)&r_lds[c][fb];
      float4 ww = *(const float4*)&wout_s[o][NI + fb];
      s = fmaf(ww.x, rr.x, s); s = fmaf(ww.y, rr.y, s);
      s = fmaf(ww.z, rr.z, s); s = fmaf(ww.w, rr.w, s);
    }
    #pragma unroll
    for (int e = 0; e < 4; ++e)
      s = fmaf(wout_s[o][4 * j + e], x_lds[(NS - 1) % 3][c][4 * j + e], s);
    s += __shfl_xor(s, 1); s += __shfl_xor(s, 2);
    s += __shfl_xor(s, 4); s += __shfl_xor(s, 8);
    if (j == 0) out[((size_t)(4 * g + c) * NS + (NS - 1)) * NO + o] = s;
  }
}

extern "C" void kernel_launch(void* const* d_in, const int* in_sizes, int n_in,
                              void* d_out, int out_size, void* d_ws, size_t ws_size,
                              hipStream_t stream) {
  const float* x    = (const float*)d_in[0];
  const float* Win  = (const float*)d_in[1];
  const float* Wres = (const float*)d_in[2];
  const float* Wout = (const float*)d_in[3];
  float* out = (float*)d_out;

  char* ws = (char*)d_ws;
  unsigned int* cnt = (unsigned int*)ws;      // 4 KB barrier counters
  float* rbuf = (float*)(ws + 4096);          // 2*32*1024*4 = 256 KB

  hipLaunchKernelGGL(init_cnt_kernel, dim3(1), dim3(1024), 0, stream, cnt);
  hipLaunchKernelGGL(esn_scan, dim3(256), dim3(NT), 64 * 1024, stream,
                     x, Win, Wres, Wout, out, cnt, rbuf);
}

// Round 17
// 11207.696 us; speedup vs baseline: 1.4975x; 1.0616x over previous
//
#include <hip/hip_runtime.h>
#include <hip/hip_fp16.h>
#include <math.h>

// EchoStateNetwork: B=32, S=4096, I=64, R=1024, O=8, fp32.
// r15 structure (proven 11.90 ms) + v_dot2_f32_f16 recurrent dot.
// r_{t-1} packed to half2 at gather (cvt_pkrtz) and stored in LDS as
// half2; weights already half2 -> inner loop = 128 fdot2 + 16 ds_read_b64
// (was 256 v_fma + 64 v_cvt + 16 ds_read_b128). Rotating reducer fdot2
// (packed fp16 W_out r-part; shadow path). Everything else identical to
// r15: fp32 rbuf transport via RELAXED agent atomics, counter barrier
// arrive-early/wait-late, parallel pin (fp32), mod-3 x ring, 64KB dynamic
// LDS pad -> 1 WG/CU.
// r16 fix: h2 typedef is __fp16-based (cvt_pkrtz's native return type).

#define NS 4096
#define NI 64
#define NR 1024
#define NO 8
#define NB 32
#define NGRP 8
#define GPP 32      // WGs per group
#define CPG 4       // chains per group
#define WROWS 32    // W_res rows per WG
#define NT 512
#define XPAD 68     // padded row stride (272B, 16B-aligned)

typedef __fp16 h2 __attribute__((ext_vector_type(2)));
union UH2 { unsigned u; h2 h; };
union ULF2 { unsigned long long u; float2 f; };

#define ATSF(p,v) __hip_atomic_store((p), (v), __ATOMIC_RELAXED, __HIP_MEMORY_SCOPE_AGENT)
#define ATLU(p)   __hip_atomic_load((p), __ATOMIC_RELAXED, __HIP_MEMORY_SCOPE_AGENT)
#define ATLU64(p) __hip_atomic_load((p), __ATOMIC_RELAXED, __HIP_MEMORY_SCOPE_AGENT)
#define ATAU(p,v) __hip_atomic_fetch_add((p), (v), __ATOMIC_RELAXED, __HIP_MEMORY_SCOPE_AGENT)

static __device__ __forceinline__ h2 u2h(unsigned u) { UH2 t; t.u = u; return t.h; }

__global__ void init_cnt_kernel(unsigned int* cnt) {
  cnt[threadIdx.x] = 0u;   // zero 4 KB of barrier counters
}

__global__ __launch_bounds__(NT)
__attribute__((amdgpu_waves_per_eu(2, 2)))
void esn_scan(const float* __restrict__ x, const float* __restrict__ Win,
              const float* __restrict__ Wres, const float* __restrict__ Wout,
              float* __restrict__ out, unsigned int* __restrict__ cnt,
              float* __restrict__ rbuf)
{
  extern __shared__ float dynpad[];  // 64 KB occupancy shaping (dispatch-reserved)
  const int wg  = blockIdx.x;
  const int g   = wg & 7;    // group
  const int m   = wg >> 3;   // member 0..31
  const int tid = threadIdx.x;
  const int w   = tid >> 6;  // wave 0..7
  const int l   = tid & 63;  // lane

  __shared__ unsigned r_h[CPG][NR / 2];    // 8 KB: r_{t-1} as half2 pairs
  __shared__ float x_lds[3][CPG][XPAD];    // mod-3 ring (272B rows, aligned)
  __shared__ float win_s[WROWS][XPAD];     // 8.7 KB
  __shared__ unsigned woutr_h[NO][NR / 2]; // 16 KB: W_out r-part as half2
  __shared__ float woutx_s[NO][NI];        // 2 KB: W_out x-part fp32

  // never-true guard keeps dynpad referenced
  if (x[0] == 1234.5678f) { dynpad[tid] = 1.f; out[tid] = dynpad[tid ^ 1]; }

  // ---- startup: weights -> fp16 pairs (regs/LDS) ----
  h2 wh[32];  // wh[(r*4+s)*2+p] = W_res[32m+4w+r][4l+256s+2p .. +1]
  {
    const int grow0 = 32 * m + 4 * w;
    #pragma unroll
    for (int r = 0; r < 4; ++r)
      #pragma unroll
      for (int s = 0; s < 4; ++s) {
        float4 t4 = *(const float4*)&Wres[(size_t)(grow0 + r) * NR + 4 * l + 256 * s];
        wh[(r * 4 + s) * 2 + 0] = __builtin_amdgcn_cvt_pkrtz(t4.x, t4.y);
        wh[(r * 4 + s) * 2 + 1] = __builtin_amdgcn_cvt_pkrtz(t4.z, t4.w);
      }
  }
  for (int idx = tid; idx < WROWS * NI; idx += NT) {
    int rr = idx >> 6, ii = idx & 63;
    win_s[rr][ii] = Win[(32 * m + rr) * NI + ii];
  }
  for (int idx = tid; idx < NO * (NR / 2); idx += NT) {
    int o = idx >> 9, p = idx & 511;
    UH2 t; t.h = __builtin_amdgcn_cvt_pkrtz(Wout[o * (NI + NR) + NI + 2 * p],
                                            Wout[o * (NI + NR) + NI + 2 * p + 1]);
    woutr_h[o][p] = t.u;
  }
  if (tid < NO * NI) {
    int o = tid >> 6, ii = tid & 63;
    woutx_s[o][ii] = Wout[o * (NI + NR) + ii];
  }
  if (tid < 256) {  // x[0] into ring slot 0
    const int c = tid >> 6, ii = tid & 63;
    x_lds[0][c][ii] = x[(size_t)(4 * g + c) * NS * NI + ii];
  }
  __syncthreads();

  unsigned int* bcp = cnt + g * 64;  // barrier counter (256 B apart per group)

  for (int t = 0; t < NS; ++t) {
    const int par = t & 1, pprev = par ^ 1;

    // ---- Phase L: gather r_{t-1} (agent b64 loads) -> pack half2 -> LDS ----
    if (t > 0) {
      const unsigned long long* rq =
        (const unsigned long long*)(rbuf + (size_t)pprev * NB * NR + (size_t)(4 * g) * NR);
      unsigned long long uv[4];
      #pragma unroll
      for (int c = 0; c < 4; ++c) uv[c] = ATLU64(rq + c * 512 + tid);
      #pragma unroll
      for (int c = 0; c < 4; ++c) {
        ULF2 t2; t2.u = uv[c];
        UH2 hpack; hpack.h = __builtin_amdgcn_cvt_pkrtz(t2.f.x, t2.f.y);
        r_h[c][tid] = hpack.u;   // pair p = tid of chain c
      }
    } else {
      #pragma unroll
      for (int c = 0; c < 4; ++c) r_h[c][tid] = 0u;
    }
    __syncthreads();

    // ---- dot: acc[r][c] via v_dot2_f32_f16 (16 cols/thread) ----
    float acc[4][4];
    #pragma unroll
    for (int r = 0; r < 4; ++r)
      #pragma unroll
      for (int c = 0; c < 4; ++c) acc[r][c] = 0.f;
    #pragma unroll
    for (int s = 0; s < 4; ++s) {
      uint2 q0 = *(const uint2*)&r_h[0][2 * l + 128 * s];
      uint2 q1 = *(const uint2*)&r_h[1][2 * l + 128 * s];
      uint2 q2 = *(const uint2*)&r_h[2][2 * l + 128 * s];
      uint2 q3 = *(const uint2*)&r_h[3][2 * l + 128 * s];
      #pragma unroll
      for (int r = 0; r < 4; ++r) {
        const h2 wa = wh[(r * 4 + s) * 2 + 0];
        const h2 wb = wh[(r * 4 + s) * 2 + 1];
        acc[r][0] = __builtin_amdgcn_fdot2(wa, u2h(q0.x), acc[r][0], false);
        acc[r][0] = __builtin_amdgcn_fdot2(wb, u2h(q0.y), acc[r][0], false);
        acc[r][1] = __builtin_amdgcn_fdot2(wa, u2h(q1.x), acc[r][1], false);
        acc[r][1] = __builtin_amdgcn_fdot2(wb, u2h(q1.y), acc[r][1], false);
        acc[r][2] = __builtin_amdgcn_fdot2(wa, u2h(q2.x), acc[r][2], false);
        acc[r][2] = __builtin_amdgcn_fdot2(wb, u2h(q2.y), acc[r][2], false);
        acc[r][3] = __builtin_amdgcn_fdot2(wa, u2h(q3.x), acc[r][3], false);
        acc[r][3] = __builtin_amdgcn_fdot2(wb, u2h(q3.y), acc[r][3], false);
      }
    }

    // ---- paired butterfly: 16 sums across 64 lanes ----
    float v[16];
    #pragma unroll
    for (int k = 0; k < 16; ++k) v[k] = acc[k >> 2][k & 3];
    #pragma unroll
    for (int lev = 0; lev < 4; ++lev) {
      const int d = 1 << lev;
      const int n = 16 >> lev;
      #pragma unroll
      for (int i = 0; i < n / 2; ++i) {
        float a  = v[2 * i]     + __shfl_xor(v[2 * i],     d);
        float bb = v[2 * i + 1] + __shfl_xor(v[2 * i + 1], d);
        v[i] = (l & d) ? bb : a;
      }
    }
    float dsum = v[0];
    dsum += __shfl_xor(dsum, 16);
    dsum += __shfl_xor(dsum, 32);

    // ---- parallel pin: pair p=l&15 (row 4w+(p>>2), chain p&3), chunk l>>4 ----
    float pin;
    {
      const int p = l & 15;
      const int prow = 4 * w + (p >> 2);
      const int pc = p & 3;
      const int cb = (l >> 4) * 16;
      const float* wr = &win_s[prow][cb];
      const float* xr = &x_lds[t % 3][pc][cb];
      float4 a0 = *(const float4*)&wr[0];
      float4 a1 = *(const float4*)&wr[4];
      float4 a2 = *(const float4*)&wr[8];
      float4 a3 = *(const float4*)&wr[12];
      float4 b0 = *(const float4*)&xr[0];
      float4 b1 = *(const float4*)&xr[4];
      float4 b2 = *(const float4*)&xr[8];
      float4 b3 = *(const float4*)&xr[12];
      pin = a0.x * b0.x;
      pin = fmaf(a0.y, b0.y, pin); pin = fmaf(a0.z, b0.z, pin);
      pin = fmaf(a0.w, b0.w, pin);
      pin = fmaf(a1.x, b1.x, pin); pin = fmaf(a1.y, b1.y, pin);
      pin = fmaf(a1.z, b1.z, pin); pin = fmaf(a1.w, b1.w, pin);
      pin = fmaf(a2.x, b2.x, pin); pin = fmaf(a2.y, b2.y, pin);
      pin = fmaf(a2.z, b2.z, pin); pin = fmaf(a2.w, b2.w, pin);
      pin = fmaf(a3.x, b3.x, pin); pin = fmaf(a3.y, b3.y, pin);
      pin = fmaf(a3.z, b3.z, pin); pin = fmaf(a3.w, b3.w, pin);
      pin += __shfl_xor(pin, 16);
      pin += __shfl_xor(pin, 32);
    }

    // ---- finalize: tanh + relaxed agent store (fp32 transport, proven) ----
    if (l < 16) {
      const int r = l >> 2, c = l & 3;
      const int grow = 32 * m + 4 * w + r;
      float rv = tanhf(dsum + pin);
      ATSF(rbuf + (size_t)par * NB * NR + (size_t)(4 * g + c) * NR + grow, rv);
    }

    // ---- arrive (early): __syncthreads drains vmcnt(0) first ----
    __syncthreads();
    if (tid == 0) ATAU(bcp, 1u);

    // ---- shadow work while the group converges ----
    if (t + 1 < NS && tid < 256) {
      const int c = tid >> 6, ii = tid & 63;
      x_lds[(t + 1) % 3][c][ii] = x[((size_t)(4 * g + c) * NS + (t + 1)) * NI + ii];
    }
    if (t > 0 && m == ((t - 1) & 31)) {   // rotating local output reduction
      const int grp = tid >> 4;   // 0..31 -> (c,o)
      const int j   = tid & 15;
      const int c   = grp >> 3, o = grp & 7;
      float s = 0.f;
      #pragma unroll
      for (int k = 0; k < 16; ++k) {
        uint2 rr = *(const uint2*)&r_h[c][32 * k + 2 * j];
        uint2 ww = *(const uint2*)&woutr_h[o][32 * k + 2 * j];
        s = __builtin_amdgcn_fdot2(u2h(rr.x), u2h(ww.x), s, false);
        s = __builtin_amdgcn_fdot2(u2h(rr.y), u2h(ww.y), s, false);
      }
      #pragma unroll
      for (int e = 0; e < 4; ++e)
        s = fmaf(woutx_s[o][4 * j + e], x_lds[(t + 2) % 3][c][4 * j + e], s);
      s += __shfl_xor(s, 1); s += __shfl_xor(s, 2);
      s += __shfl_xor(s, 4); s += __shfl_xor(s, 8);
      if (j == 0) out[((size_t)(4 * g + c) * NS + (t - 1)) * NO + o] = s;
    }

    // ---- wait (late) ----
    if (tid == 0) {
      const unsigned target = (unsigned)(GPP * (t + 1));
      while (ATLU(bcp) < target) { }
    }
    __syncthreads();
  }

  // ---- final output row t = NS-1 (one WG per group; r_{NS-1} from rbuf) ----
  if (m == 31) {
    const int fpar = (NS - 1) & 1;
    const unsigned long long* rq =
      (const unsigned long long*)(rbuf + (size_t)fpar * NB * NR + (size_t)(4 * g) * NR);
    unsigned long long uv[4];
    #pragma unroll
    for (int c = 0; c < 4; ++c) uv[c] = ATLU64(rq + c * 512 + tid);
    #pragma unroll
    for (int c = 0; c < 4; ++c) {
      ULF2 t2; t2.u = uv[c];
      UH2 hpack; hpack.h = __builtin_amdgcn_cvt_pkrtz(t2.f.x, t2.f.y);
      r_h[c][tid] = hpack.u;
    }
    __syncthreads();
    const int grp = tid >> 4;
    const int j   = tid & 15;
    const int c   = grp >> 3, o = grp & 7;
    float s = 0.f;
    #pragma unroll
    for (int k = 0; k < 16; ++k) {
      uint2 rr = *(const uint2*)&r_h[c][32 * k + 2 * j];
      uint2 ww = *(const uint2*)&woutr_h[o][32 * k + 2 * j];
      s = __builtin_amdgcn_fdot2(u2h(rr.x), u2h(ww.x), s, false);
      s = __builtin_amdgcn_fdot2(u2h(rr.y), u2h(ww.y), s, false);
    }
    #pragma unroll
    for (int e = 0; e < 4; ++e)
      s = fmaf(woutx_s[o][4 * j + e], x_lds[(NS - 1) % 3][c][4 * j + e], s);
    s += __shfl_xor(s, 1); s += __shfl_xor(s, 2);
    s += __shfl_xor(s, 4); s += __shfl_xor(s, 8);
    if (j == 0) out[((size_t)(4 * g + c) * NS + (NS - 1)) * NO + o] = s;
  }
}

extern "C" void kernel_launch(void* const* d_in, const int* in_sizes, int n_in,
                              void* d_out, int out_size, void* d_ws, size_t ws_size,
                              hipStream_t stream) {
  const float* x    = (const float*)d_in[0];
  const float* Win  = (const float*)d_in[1];
  const float* Wres = (const float*)d_in[2];
  const float* Wout = (const float*)d_in[3];
  float* out = (float*)d_out;

  char* ws = (char*)d_ws;
  unsigned int* cnt = (unsigned int*)ws;      // 4 KB barrier counters
  float* rbuf = (float*)(ws + 4096);          // 2*32*1024*4 = 256 KB

  hipLaunchKernelGGL(init_cnt_kernel, dim3(1), dim3(1024), 0, stream, cnt);
  hipLaunchKernelGGL(esn_scan, dim3(256), dim3(NT), 64 * 1024, stream,
                     x, Win, Wres, Wout, out, cnt, rbuf);
}

// Round 18
// 10119.138 us; speedup vs baseline: 1.6586x; 1.1076x over previous
//
#include <hip/hip_runtime.h>
#include <hip/hip_fp16.h>
#include <math.h>

// EchoStateNetwork: B=32, S=4096, I=64, R=1024, O=8, fp32.
// r17 (proven 11.21 ms) + two protocol cuts:
//  (1) fp16 rbuf transport: rv packed to half2 at STORE time (cvt_pkrtz +
//      shfl_xor(4) pair-up; 8 u32 stores/wave); gather = 4 b32 agent loads
//      -> r_h LDS directly (no load-side pack). Consumers already fp16 ->
//      bit-identical results.
//  (2) 4-line arrive: per-group counter split over 4 lines 256B apart
//      (8 RMWs/line, not 32 serialized); poll = 4 independent loads.
// Everything else identical to r17: fdot2 dot, parallel pin (fp32),
// arrive-early/wait-late, shadow reducer + x ring, 64KB dynamic LDS pad.

#define NS 4096
#define NI 64
#define NR 1024
#define NO 8
#define NB 32
#define NGRP 8
#define GPP 32      // WGs per group
#define CPG 4       // chains per group
#define WROWS 32    // W_res rows per WG
#define NT 512
#define XPAD 68     // padded row stride (272B, 16B-aligned)

typedef __fp16 h2 __attribute__((ext_vector_type(2)));
union UH2 { unsigned u; h2 h; };

#define ATSU(p,v) __hip_atomic_store((p), (v), __ATOMIC_RELAXED, __HIP_MEMORY_SCOPE_AGENT)
#define ATLU(p)   __hip_atomic_load((p), __ATOMIC_RELAXED, __HIP_MEMORY_SCOPE_AGENT)
#define ATAU(p,v) __hip_atomic_fetch_add((p), (v), __ATOMIC_RELAXED, __HIP_MEMORY_SCOPE_AGENT)

static __device__ __forceinline__ h2 u2h(unsigned u) { UH2 t; t.u = u; return t.h; }

__global__ void init_cnt_kernel(unsigned int* cnt) {
  cnt[threadIdx.x] = 0u;           // zero 8 KB: 8 groups x 4 lines x 64 dwords
  cnt[threadIdx.x + 1024] = 0u;
}

__global__ __launch_bounds__(NT)
__attribute__((amdgpu_waves_per_eu(2, 2)))
void esn_scan(const float* __restrict__ x, const float* __restrict__ Win,
              const float* __restrict__ Wres, const float* __restrict__ Wout,
              float* __restrict__ out, unsigned int* __restrict__ cnt,
              unsigned int* __restrict__ rbuf_h)
{
  extern __shared__ float dynpad[];  // 64 KB occupancy shaping (dispatch-reserved)
  const int wg  = blockIdx.x;
  const int g   = wg & 7;    // group
  const int m   = wg >> 3;   // member 0..31
  const int tid = threadIdx.x;
  const int w   = tid >> 6;  // wave 0..7
  const int l   = tid & 63;  // lane

  __shared__ unsigned r_h[CPG][NR / 2];    // 8 KB: r_{t-1} as half2 pairs
  __shared__ float x_lds[3][CPG][XPAD];    // mod-3 ring (272B rows, aligned)
  __shared__ float win_s[WROWS][XPAD];     // 8.7 KB
  __shared__ unsigned woutr_h[NO][NR / 2]; // 16 KB: W_out r-part as half2
  __shared__ float woutx_s[NO][NI];        // 2 KB: W_out x-part fp32

  // never-true guard keeps dynpad referenced
  if (x[0] == 1234.5678f) { dynpad[tid] = 1.f; out[tid] = dynpad[tid ^ 1]; }

  // ---- startup: weights -> fp16 pairs (regs/LDS) ----
  h2 wh[32];  // wh[(r*4+s)*2+p] = W_res[32m+4w+r][4l+256s+2p .. +1]
  {
    const int grow0 = 32 * m + 4 * w;
    #pragma unroll
    for (int r = 0; r < 4; ++r)
      #pragma unroll
      for (int s = 0; s < 4; ++s) {
        float4 t4 = *(const float4*)&Wres[(size_t)(grow0 + r) * NR + 4 * l + 256 * s];
        wh[(r * 4 + s) * 2 + 0] = __builtin_amdgcn_cvt_pkrtz(t4.x, t4.y);
        wh[(r * 4 + s) * 2 + 1] = __builtin_amdgcn_cvt_pkrtz(t4.z, t4.w);
      }
  }
  for (int idx = tid; idx < WROWS * NI; idx += NT) {
    int rr = idx >> 6, ii = idx & 63;
    win_s[rr][ii] = Win[(32 * m + rr) * NI + ii];
  }
  for (int idx = tid; idx < NO * (NR / 2); idx += NT) {
    int o = idx >> 9, p = idx & 511;
    UH2 t; t.h = __builtin_amdgcn_cvt_pkrtz(Wout[o * (NI + NR) + NI + 2 * p],
                                            Wout[o * (NI + NR) + NI + 2 * p + 1]);
    woutr_h[o][p] = t.u;
  }
  if (tid < NO * NI) {
    int o = tid >> 6, ii = tid & 63;
    woutx_s[o][ii] = Wout[o * (NI + NR) + ii];
  }
  if (tid < 256) {  // x[0] into ring slot 0
    const int c = tid >> 6, ii = tid & 63;
    x_lds[0][c][ii] = x[(size_t)(4 * g + c) * NS * NI + ii];
  }
  __syncthreads();

  unsigned int* bcp = cnt + (g * 4 + (m & 3)) * 64;  // my arrive line
  unsigned int* pol = cnt + g * 4 * 64;              // poll base (4 lines)

  for (int t = 0; t < NS; ++t) {
    const int par = t & 1, pprev = par ^ 1;

    // ---- Phase L: gather r_{t-1} (4 agent b32 loads -> LDS, pre-packed) ----
    if (t > 0) {
      const unsigned* rq = rbuf_h + (size_t)pprev * NB * (NR / 2)
                                  + (size_t)(4 * g) * (NR / 2);
      unsigned uv[4];
      #pragma unroll
      for (int c = 0; c < 4; ++c) uv[c] = ATLU(rq + c * 512 + tid);
      #pragma unroll
      for (int c = 0; c < 4; ++c) r_h[c][tid] = uv[c];
    } else {
      #pragma unroll
      for (int c = 0; c < 4; ++c) r_h[c][tid] = 0u;
    }
    __syncthreads();

    // ---- dot: acc[r][c] via v_dot2_f32_f16 (16 cols/thread) ----
    float acc[4][4];
    #pragma unroll
    for (int r = 0; r < 4; ++r)
      #pragma unroll
      for (int c = 0; c < 4; ++c) acc[r][c] = 0.f;
    #pragma unroll
    for (int s = 0; s < 4; ++s) {
      uint2 q0 = *(const uint2*)&r_h[0][2 * l + 128 * s];
      uint2 q1 = *(const uint2*)&r_h[1][2 * l + 128 * s];
      uint2 q2 = *(const uint2*)&r_h[2][2 * l + 128 * s];
      uint2 q3 = *(const uint2*)&r_h[3][2 * l + 128 * s];
      #pragma unroll
      for (int r = 0; r < 4; ++r) {
        const h2 wa = wh[(r * 4 + s) * 2 + 0];
        const h2 wb = wh[(r * 4 + s) * 2 + 1];
        acc[r][0] = __builtin_amdgcn_fdot2(wa, u2h(q0.x), acc[r][0], false);
        acc[r][0] = __builtin_amdgcn_fdot2(wb, u2h(q0.y), acc[r][0], false);
        acc[r][1] = __builtin_amdgcn_fdot2(wa, u2h(q1.x), acc[r][1], false);
        acc[r][1] = __builtin_amdgcn_fdot2(wb, u2h(q1.y), acc[r][1], false);
        acc[r][2] = __builtin_amdgcn_fdot2(wa, u2h(q2.x), acc[r][2], false);
        acc[r][2] = __builtin_amdgcn_fdot2(wb, u2h(q2.y), acc[r][2], false);
        acc[r][3] = __builtin_amdgcn_fdot2(wa, u2h(q3.x), acc[r][3], false);
        acc[r][3] = __builtin_amdgcn_fdot2(wb, u2h(q3.y), acc[r][3], false);
      }
    }

    // ---- paired butterfly: 16 sums across 64 lanes ----
    float v[16];
    #pragma unroll
    for (int k = 0; k < 16; ++k) v[k] = acc[k >> 2][k & 3];
    #pragma unroll
    for (int lev = 0; lev < 4; ++lev) {
      const int d = 1 << lev;
      const int n = 16 >> lev;
      #pragma unroll
      for (int i = 0; i < n / 2; ++i) {
        float a  = v[2 * i]     + __shfl_xor(v[2 * i],     d);
        float bb = v[2 * i + 1] + __shfl_xor(v[2 * i + 1], d);
        v[i] = (l & d) ? bb : a;
      }
    }
    float dsum = v[0];
    dsum += __shfl_xor(dsum, 16);
    dsum += __shfl_xor(dsum, 32);

    // ---- parallel pin: pair p=l&15 (row 4w+(p>>2), chain p&3), chunk l>>4 ----
    float pin;
    {
      const int p = l & 15;
      const int prow = 4 * w + (p >> 2);
      const int pc = p & 3;
      const int cb = (l >> 4) * 16;
      const float* wr = &win_s[prow][cb];
      const float* xr = &x_lds[t % 3][pc][cb];
      float4 a0 = *(const float4*)&wr[0];
      float4 a1 = *(const float4*)&wr[4];
      float4 a2 = *(const float4*)&wr[8];
      float4 a3 = *(const float4*)&wr[12];
      float4 b0 = *(const float4*)&xr[0];
      float4 b1 = *(const float4*)&xr[4];
      float4 b2 = *(const float4*)&xr[8];
      float4 b3 = *(const float4*)&xr[12];
      pin = a0.x * b0.x;
      pin = fmaf(a0.y, b0.y, pin); pin = fmaf(a0.z, b0.z, pin);
      pin = fmaf(a0.w, b0.w, pin);
      pin = fmaf(a1.x, b1.x, pin); pin = fmaf(a1.y, b1.y, pin);
      pin = fmaf(a1.z, b1.z, pin); pin = fmaf(a1.w, b1.w, pin);
      pin = fmaf(a2.x, b2.x, pin); pin = fmaf(a2.y, b2.y, pin);
      pin = fmaf(a2.z, b2.z, pin); pin = fmaf(a2.w, b2.w, pin);
      pin = fmaf(a3.x, b3.x, pin); pin = fmaf(a3.y, b3.y, pin);
      pin = fmaf(a3.z, b3.z, pin); pin = fmaf(a3.w, b3.w, pin);
      pin += __shfl_xor(pin, 16);
      pin += __shfl_xor(pin, 32);
    }

    // ---- finalize: tanh (all lanes) + pack half2 + agent store ----
    {
      float rv = tanhf(dsum + pin);          // lane l: value for pair l&15
      float rvo = __shfl_xor(rv, 4);         // partner row (r^1), same chain
      if (l < 16 && ((l >> 2) & 1) == 0) {   // r even: pack (row r, row r+1)
        const int r = l >> 2, c = l & 3;
        UH2 hp; hp.h = __builtin_amdgcn_cvt_pkrtz(rv, rvo);
        const int pair = 16 * m + 2 * w + (r >> 1);
        ATSU(rbuf_h + (size_t)par * NB * (NR / 2)
                    + (size_t)(4 * g + c) * (NR / 2) + pair, hp.u);
      }
    }

    // ---- arrive (early): __syncthreads drains vmcnt(0) first ----
    __syncthreads();
    if (tid == 0) ATAU(bcp, 1u);

    // ---- shadow work while the group converges ----
    if (t + 1 < NS && tid < 256) {
      const int c = tid >> 6, ii = tid & 63;
      x_lds[(t + 1) % 3][c][ii] = x[((size_t)(4 * g + c) * NS + (t + 1)) * NI + ii];
    }
    if (t > 0 && m == ((t - 1) & 31)) {   // rotating local output reduction
      const int grp = tid >> 4;   // 0..31 -> (c,o)
      const int j   = tid & 15;
      const int c   = grp >> 3, o = grp & 7;
      float s = 0.f;
      #pragma unroll
      for (int k = 0; k < 16; ++k) {
        uint2 rr = *(const uint2*)&r_h[c][32 * k + 2 * j];
        uint2 ww = *(const uint2*)&woutr_h[o][32 * k + 2 * j];
        s = __builtin_amdgcn_fdot2(u2h(rr.x), u2h(ww.x), s, false);
        s = __builtin_amdgcn_fdot2(u2h(rr.y), u2h(ww.y), s, false);
      }
      #pragma unroll
      for (int e = 0; e < 4; ++e)
        s = fmaf(woutx_s[o][4 * j + e], x_lds[(t + 2) % 3][c][4 * j + e], s);
      s += __shfl_xor(s, 1); s += __shfl_xor(s, 2);
      s += __shfl_xor(s, 4); s += __shfl_xor(s, 8);
      if (j == 0) out[((size_t)(4 * g + c) * NS + (t - 1)) * NO + o] = s;
    }

    // ---- wait (late): 4 independent line polls, ~1 round trip each loop ----
    if (tid == 0) {
      const unsigned tg = 8u * (unsigned)(t + 1);
      for (;;) {
        unsigned u0 = ATLU(pol);
        unsigned u1 = ATLU(pol + 64);
        unsigned u2 = ATLU(pol + 128);
        unsigned u3 = ATLU(pol + 192);
        if (u0 >= tg && u1 >= tg && u2 >= tg && u3 >= tg) break;
      }
    }
    __syncthreads();
  }

  // ---- final output row t = NS-1 (one WG per group; r from rbuf_h) ----
  if (m == 31) {
    const int fpar = (NS - 1) & 1;
    const unsigned* rq = rbuf_h + (size_t)fpar * NB * (NR / 2)
                                + (size_t)(4 * g) * (NR / 2);
    unsigned uv[4];
    #pragma unroll
    for (int c = 0; c < 4; ++c) uv[c] = ATLU(rq + c * 512 + tid);
    #pragma unroll
    for (int c = 0; c < 4; ++c) r_h[c][tid] = uv[c];
    __syncthreads();
    const int grp = tid >> 4;
    const int j   = tid & 15;
    const int c   = grp >> 3, o = grp & 7;
    float s = 0.f;
    #pragma unroll
    for (int k = 0; k < 16; ++k) {
      uint2 rr = *(const uint2*)&r_h[c][32 * k + 2 * j];
      uint2 ww = *(const uint2*)&woutr_h[o][32 * k + 2 * j];
      s = __builtin_amdgcn_fdot2(u2h(rr.x), u2h(ww.x), s, false);
      s = __builtin_amdgcn_fdot2(u2h(rr.y), u2h(ww.y), s, false);
    }
    #pragma unroll
    for (int e = 0; e < 4; ++e)
      s = fmaf(woutx_s[o][4 * j + e], x_lds[(NS - 1) % 3][c][4 * j + e], s);
    s += __shfl_xor(s, 1); s += __shfl_xor(s, 2);
    s += __shfl_xor(s, 4); s += __shfl_xor(s, 8);
    if (j == 0) out[((size_t)(4 * g + c) * NS + (NS - 1)) * NO + o] = s;
  }
}

extern "C" void kernel_launch(void* const* d_in, const int* in_sizes, int n_in,
                              void* d_out, int out_size, void* d_ws, size_t ws_size,
                              hipStream_t stream) {
  const float* x    = (const float*)d_in[0];
  const float* Win  = (const float*)d_in[1];
  const float* Wres = (const float*)d_in[2];
  const float* Wout = (const float*)d_in[3];
  float* out = (float*)d_out;

  char* ws = (char*)d_ws;
  unsigned int* cnt = (unsigned int*)ws;          // 8 KB: 8 groups x 4 lines
  unsigned int* rbuf_h = (unsigned int*)(ws + 8192);  // 2*32*512*4 = 128 KB

  hipLaunchKernelGGL(init_cnt_kernel, dim3(1), dim3(1024), 0, stream, cnt);
  hipLaunchKernelGGL(esn_scan, dim3(256), dim3(NT), 64 * 1024, stream,
                     x, Win, Wres, Wout, out, cnt, rbuf_h);
}